// Round 2
// baseline (602.496 us; speedup 1.0000x reference)
//
#include <hip/hip_runtime.h>

#define BB 4
#define SS 2048
#define DD 256
#define HH 8

typedef unsigned short u16;
typedef __attribute__((ext_vector_type(8))) short bf16x8;
typedef __attribute__((ext_vector_type(4))) float f32x4;

__device__ __forceinline__ f32x4 MFMA(bf16x8 a, bf16x8 b, f32x4 c) {
    return __builtin_amdgcn_mfma_f32_16x16x32_bf16(a, b, c, 0, 0, 0);
}

__device__ __forceinline__ u16 f2bf_rtn(float x) {
    unsigned u = __float_as_uint(x);
    u += 0x7FFFu + ((u >> 16) & 1u);
    return (u16)(u >> 16);
}
__device__ __forceinline__ float bf2f(u16 h) {
    return __uint_as_float(((unsigned)h) << 16);
}
__device__ __forceinline__ void split2(float x, u16 &hi, u16 &lo) {
    hi = f2bf_rtn(x);
    lo = f2bf_rtn(x - bf2f(hi));
}

// ---------------- weight prep: transpose + hi/lo split ----------------
// W [H][D][D] (y = x @ W[h]) -> Wt[n = h*256 + e][k = d], hi/lo planes
__global__ void prep_w(const float* __restrict__ W, u16* __restrict__ Whi,
                       u16* __restrict__ Wlo) {
    int n = blockIdx.x;            // 0..2047
    int h = n >> 8, e = n & 255;
    int d = threadIdx.x;           // 0..255
    float x = W[((size_t)h * 256 + d) * 256 + e];
    u16 hi, lo; split2(x, hi, lo);
    Whi[(size_t)n * 256 + d] = hi;
    Wlo[(size_t)n * 256 + d] = lo;
}

// Wo [2048][256] -> Wt[n=0..255][k=0..2047]
__global__ void prep_wo(const float* __restrict__ W, u16* __restrict__ Whi,
                        u16* __restrict__ Wlo) {
    int n = blockIdx.x;            // 0..255
    for (int k = threadIdx.x; k < 2048; k += 256) {
        float x = W[(size_t)k * 256 + n];
        u16 hi, lo; split2(x, hi, lo);
        Whi[(size_t)n * 2048 + k] = hi;
        Wlo[(size_t)n * 2048 + k] = lo;
    }
}

// ---------------- split-bf16 GEMM: C = A * B^T(stored [N][K]) + bias ----------------
// MODE 0: bf16-hi output -> Q/K layout [b][h][s][d]
// MODE 1: bf16-hi output -> V^T layout [b][h][d][s]
// MODE 2: fp32 output    -> C[row*N + col]
// TERMS 1: ah*bh            (Q/K proj)
// TERMS 2: ah*bh + ah*bl    (V proj: weight split matters, A-side doesn't)
// TERMS 3: ah*bh + al*bh + ah*bl  (out proj: R split + Wo split)
template<int MODE, bool AFP32, int TERMS>
__global__ __launch_bounds__(512, 2) void gemm_split(
    const float* __restrict__ Af,
    const u16* __restrict__ Ahi, const u16* __restrict__ Alo,
    const u16* __restrict__ Bhi, const u16* __restrict__ Blo,
    const float* __restrict__ bias,
    u16* __restrict__ Ohi,
    float* __restrict__ Of,
    int M, int N, int K, float scale)
{
    __shared__ u16 lA_hi[128][40], lA_lo[128][40];
    __shared__ u16 lB_hi[128][40], lB_lo[128][40];

    const int tid = threadIdx.x;
    const int lane = tid & 63, wave = tid >> 6;
    const int wm = wave >> 2, wn = wave & 3;       // 2 x 4 waves, 64x32 each
    const int m0 = blockIdx.y * 128, n0 = blockIdx.x * 128;

    f32x4 acc[4][2];
#pragma unroll
    for (int i = 0; i < 4; ++i)
#pragma unroll
        for (int j = 0; j < 2; ++j) acc[i][j] = {0.f, 0.f, 0.f, 0.f};

    const int srow = tid >> 2;
    const int schunk = (tid & 3) * 8;

    for (int k0 = 0; k0 < K; k0 += 32) {
        __syncthreads();
        if (AFP32) {
            const float* g = Af + (size_t)(m0 + srow) * K + k0 + schunk;
            f32x4 a0 = *(const f32x4*)g;
            f32x4 a1 = *(const f32x4*)(g + 4);
            bf16x8 hv;
#pragma unroll
            for (int j = 0; j < 4; ++j) hv[j] = (short)f2bf_rtn(a0[j]);
#pragma unroll
            for (int j = 0; j < 4; ++j) hv[4 + j] = (short)f2bf_rtn(a1[j]);
            *(bf16x8*)&lA_hi[srow][schunk] = hv;
        } else {
            size_t ga = (size_t)(m0 + srow) * K + k0 + schunk;
            *(bf16x8*)&lA_hi[srow][schunk] = *(const bf16x8*)(Ahi + ga);
            if (TERMS == 3)
                *(bf16x8*)&lA_lo[srow][schunk] = *(const bf16x8*)(Alo + ga);
        }
        {
            size_t gb = (size_t)(n0 + srow) * K + k0 + schunk;
            *(bf16x8*)&lB_hi[srow][schunk] = *(const bf16x8*)(Bhi + gb);
            if (TERMS >= 2)
                *(bf16x8*)&lB_lo[srow][schunk] = *(const bf16x8*)(Blo + gb);
        }
        __syncthreads();

        const int kf = (lane >> 4) * 8;
        const int rA = wm * 64, rB = wn * 32;
        bf16x8 bh[2], bl[2];
#pragma unroll
        for (int ns = 0; ns < 2; ++ns) {
            bh[ns] = *(bf16x8*)&lB_hi[rB + ns * 16 + (lane & 15)][kf];
            if (TERMS >= 2)
                bl[ns] = *(bf16x8*)&lB_lo[rB + ns * 16 + (lane & 15)][kf];
        }
#pragma unroll
        for (int ms = 0; ms < 4; ++ms) {
            bf16x8 ah = *(bf16x8*)&lA_hi[rA + ms * 16 + (lane & 15)][kf];
            bf16x8 al;
            if (TERMS == 3) al = *(bf16x8*)&lA_lo[rA + ms * 16 + (lane & 15)][kf];
#pragma unroll
            for (int ns = 0; ns < 2; ++ns) {
                acc[ms][ns] = MFMA(ah, bh[ns], acc[ms][ns]);
                if (TERMS == 3) acc[ms][ns] = MFMA(al, bh[ns], acc[ms][ns]);
                if (TERMS >= 2) acc[ms][ns] = MFMA(ah, bl[ns], acc[ms][ns]);
            }
        }
    }

#pragma unroll
    for (int ms = 0; ms < 4; ++ms)
#pragma unroll
        for (int ns = 0; ns < 2; ++ns)
#pragma unroll
            for (int r = 0; r < 4; ++r) {
                int row = m0 + wm * 64 + ms * 16 + (lane >> 4) * 4 + r;
                int col = n0 + wn * 32 + ns * 16 + (lane & 15);
                float v = (acc[ms][ns][r] + bias[col]) * scale;
                if (MODE == 2) {
                    Of[(size_t)row * N + col] = v;
                } else {
                    int b = row >> 11, s = row & 2047, hh = col >> 8, e = col & 255;
                    size_t idx;
                    if (MODE == 0)
                        idx = ((size_t)(b * HH + hh) * SS + s) * DD + e;
                    else
                        idx = ((size_t)(b * HH + hh) * DD + e) * SS + s;
                    Ohi[idx] = f2bf_rtn(v);
                }
            }
}

// ---------------- flash attention, bf16-hi inputs, split-bf16 rep output ----------------
__global__ __launch_bounds__(512, 2) void attn_kernel(
    const u16* __restrict__ Qhi,
    const u16* __restrict__ Khi,
    const u16* __restrict__ Vhi,
    u16* __restrict__ Rhi, u16* __restrict__ Rlo)
{
    __shared__ u16 lKh[32][264];                   // K tile [key][d], pad 8
    __shared__ u16 lVh[256][40];                   // V^T tile [e][key], pad 8
    __shared__ float lP[8][16][36];                // per-wave P [q][key]

    const int tid = threadIdx.x, lane = tid & 63, wave = tid >> 6;
    const int bh = blockIdx.y;                     // 0..31 (b*8+h)
    const size_t base = (size_t)bh * SS * DD;
    const int q0 = blockIdx.x * 128 + wave * 16;

    // Q fragments in registers (Q pre-scaled by 1/16)
    bf16x8 qh[8];
#pragma unroll
    for (int ks = 0; ks < 8; ++ks) {
        size_t ga = base + (size_t)(q0 + (lane & 15)) * DD + ks * 32 + (lane >> 4) * 8;
        qh[ks] = *(const bf16x8*)(Qhi + ga);
    }

    float m_r[4], l_r[4];
#pragma unroll
    for (int r = 0; r < 4; ++r) { m_r[r] = -3.0e38f; l_r[r] = 0.f; }
    f32x4 acc[16];
#pragma unroll
    for (int e = 0; e < 16; ++e) acc[e] = {0.f, 0.f, 0.f, 0.f};

    for (int kv = 0; kv < SS; kv += 32) {
        __syncthreads();
        // stage K tile: 32 rows x 256
        for (int i = tid; i < 1024; i += 512) {
            int r = i >> 5, c = (i & 31) * 8;
            *(bf16x8*)&lKh[r][c] = *(const bf16x8*)(Khi + base + (size_t)(kv + r) * DD + c);
        }
        // stage V^T tile: 256 rows x 32
        for (int i = tid; i < 1024; i += 512) {
            int r = i >> 2, c = (i & 3) * 8;
            *(bf16x8*)&lVh[r][c] = *(const bf16x8*)(Vhi + base + (size_t)r * SS + kv + c);
        }
        __syncthreads();

        // QK^T: 16 queries x 32 keys
        f32x4 s0 = {0.f, 0.f, 0.f, 0.f}, s1 = {0.f, 0.f, 0.f, 0.f};
#pragma unroll
        for (int ks = 0; ks < 8; ++ks) {
            int kf = ks * 32 + (lane >> 4) * 8;
            bf16x8 k0h = *(bf16x8*)&lKh[lane & 15][kf];
            bf16x8 k1h = *(bf16x8*)&lKh[16 + (lane & 15)][kf];
            s0 = MFMA(qh[ks], k0h, s0);
            s1 = MFMA(qh[ks], k1h, s1);
        }

        // online softmax: query row r lives on the 16 lanes sharing lane>>4
        float mx[4];
#pragma unroll
        for (int r = 0; r < 4; ++r) mx[r] = fmaxf(s0[r], s1[r]);
#pragma unroll
        for (int off = 1; off < 16; off <<= 1)
#pragma unroll
            for (int r = 0; r < 4; ++r)
                mx[r] = fmaxf(mx[r], __shfl_xor(mx[r], off, 64));

        float f[4], sum[4];
#pragma unroll
        for (int r = 0; r < 4; ++r) {
            float mn = fmaxf(m_r[r], mx[r]);
            f[r] = __expf(m_r[r] - mn);
            m_r[r] = mn;
            s0[r] = __expf(s0[r] - mn);
            s1[r] = __expf(s1[r] - mn);
            sum[r] = s0[r] + s1[r];
        }
#pragma unroll
        for (int off = 1; off < 16; off <<= 1)
#pragma unroll
            for (int r = 0; r < 4; ++r)
                sum[r] += __shfl_xor(sum[r], off, 64);
#pragma unroll
        for (int r = 0; r < 4; ++r) l_r[r] = l_r[r] * f[r] + sum[r];

        f32x4 fv; fv[0] = f[0]; fv[1] = f[1]; fv[2] = f[2]; fv[3] = f[3];
#pragma unroll
        for (int e = 0; e < 16; ++e) acc[e] *= fv;

        // P -> per-wave LDS (layout [q][key])
#pragma unroll
        for (int r = 0; r < 4; ++r) {
            lP[wave][(lane >> 4) * 4 + r][lane & 15] = s0[r];
            lP[wave][(lane >> 4) * 4 + r][16 + (lane & 15)] = s1[r];
        }
        // read back as A-fragment (same wave; compiler orders same-array DS ops)
        f32x4 p01 = *(f32x4*)&lP[wave][lane & 15][(lane >> 4) * 8];
        f32x4 p23 = *(f32x4*)&lP[wave][lane & 15][(lane >> 4) * 8 + 4];
        bf16x8 pa;
#pragma unroll
        for (int j = 0; j < 4; ++j) pa[j] = (short)f2bf_rtn(p01[j]);
#pragma unroll
        for (int j = 0; j < 4; ++j) pa[4 + j] = (short)f2bf_rtn(p23[j]);

        // PV: rep[q][e] += P[q][key] * V[key][e]
        const int vf = (lane >> 4) * 8;
#pragma unroll
        for (int e = 0; e < 16; ++e) {
            bf16x8 vh = *(bf16x8*)&lVh[e * 16 + (lane & 15)][vf];
            acc[e] = MFMA(pa, vh, acc[e]);
        }
    }

    // epilogue: rep / l, split hi/lo, store head-interleaved [b*S+s][e*H + h]
    const int b = bh >> 3, h = bh & 7;
    float inv[4];
#pragma unroll
    for (int r = 0; r < 4; ++r) inv[r] = 1.0f / l_r[r];
#pragma unroll
    for (int e = 0; e < 16; ++e)
#pragma unroll
        for (int r = 0; r < 4; ++r) {
            int s = q0 + (lane >> 4) * 4 + r;
            int ecol = e * 16 + (lane & 15);
            float v = acc[e][r] * inv[r];
            u16 hh2, ll2; split2(v, hh2, ll2);
            size_t idx = ((size_t)(b * SS + s)) * (DD * HH) + (size_t)ecol * HH + h;
            Rhi[idx] = hh2; Rlo[idx] = ll2;
        }
}

// ---------------- launcher ----------------
extern "C" void kernel_launch(void* const* d_in, const int* in_sizes, int n_in,
                              void* d_out, int out_size, void* d_ws, size_t ws_size,
                              hipStream_t stream)
{
    (void)in_sizes; (void)n_in; (void)out_size; (void)ws_size;
    const float* k_in = (const float*)d_in[0];
    const float* v_in = (const float*)d_in[1];
    const float* q_in = (const float*)d_in[2];
    const float* Wk   = (const float*)d_in[3];
    const float* bk   = (const float*)d_in[4];
    const float* Wv   = (const float*)d_in[5];
    const float* bv   = (const float*)d_in[6];
    const float* Wq   = (const float*)d_in[7];
    const float* bq   = (const float*)d_in[8];
    const float* Wo   = (const float*)d_in[9];
    const float* bo   = (const float*)d_in[10];
    float* out = (float*)d_out;

    // workspace layout: 8 MB weights + 5 bf16 planes (32 MB each) = 168 MB total
    char* p = (char*)d_ws;
    const size_t MB = 1024 * 1024;
    u16* WqH = (u16*)(p + 0 * MB);
    u16* WqL = (u16*)(p + 1 * MB);   // unused by GEMM (TERMS=1), kept for prep symmetry
    u16* WkH = (u16*)(p + 2 * MB);
    u16* WkL = (u16*)(p + 3 * MB);   // unused
    u16* WvH = (u16*)(p + 4 * MB);
    u16* WvL = (u16*)(p + 5 * MB);
    u16* WoH = (u16*)(p + 6 * MB);
    u16* WoL = (u16*)(p + 7 * MB);
    const size_t PB = 32 * MB;       // one bf16 plane of 4*8*2048*256 elems
    u16* QH  = (u16*)(p + 8 * MB);
    u16* KH  = (u16*)(p + 8 * MB + 1 * PB);
    u16* VTH = (u16*)(p + 8 * MB + 2 * PB);
    u16* RH  = (u16*)(p + 8 * MB + 3 * PB);
    u16* RL  = (u16*)(p + 8 * MB + 4 * PB);

    // weight prep
    prep_w<<<dim3(2048), dim3(256), 0, stream>>>(Wq, WqH, WqL);
    prep_w<<<dim3(2048), dim3(256), 0, stream>>>(Wk, WkH, WkL);
    prep_w<<<dim3(2048), dim3(256), 0, stream>>>(Wv, WvH, WvL);
    prep_wo<<<dim3(256), dim3(256), 0, stream>>>(Wo, WoH, WoL);

    // projections: M=8192, N=2048, K=256. Q scaled by 1/sqrt(D)=1/16 (exact pow2).
    gemm_split<0, true, 1><<<dim3(16, 64), dim3(512), 0, stream>>>(
        q_in, nullptr, nullptr, WqH, WqL, bq, QH, nullptr, 8192, 2048, 256, 0.0625f);
    gemm_split<0, true, 1><<<dim3(16, 64), dim3(512), 0, stream>>>(
        k_in, nullptr, nullptr, WkH, WkL, bk, KH, nullptr, 8192, 2048, 256, 1.0f);
    gemm_split<1, true, 2><<<dim3(16, 64), dim3(512), 0, stream>>>(
        v_in, nullptr, nullptr, WvH, WvL, bv, VTH, nullptr, 8192, 2048, 256, 1.0f);

    // flash attention: 16 q-tiles x 32 (b,h)
    attn_kernel<<<dim3(16, 32), dim3(512), 0, stream>>>(
        QH, KH, VTH, RH, RL);

    // output projection: M=8192, N=256, K=2048, A = R split hi/lo
    gemm_split<2, false, 3><<<dim3(2, 64), dim3(512), 0, stream>>>(
        nullptr, RH, RL, WoH, WoL, bo, nullptr, out, 8192, 256, 2048, 1.0f);
}